// Round 2
// baseline (756.926 us; speedup 1.0000x reference)
//
#include <hip/hip_runtime.h>
#include <cstdint>

typedef float fx4 __attribute__((ext_vector_type(4)));
typedef short sx8 __attribute__((ext_vector_type(8)));

#define NSTATE 16
#define SEQ_LEN 2048
#define NBATCH 32
#define MROWS 65536           // NBATCH*SEQ_LEN
#define KDIM 1024
#define N1 1072               // z(1024) + B(16) + C(16) + delta(16)
#define N1PAD 1152            // 9 tiles of 128
#define BM 128
#define BN 128
#define BK 32

__device__ __forceinline__ short f2bf(float f) {
  unsigned u = __float_as_uint(f);
  u += 0x7FFFu + ((u >> 16) & 1u);   // round-to-nearest-even
  return (short)(u >> 16);
}
__device__ __forceinline__ float bf2f(short s) {
  unsigned u = ((unsigned)(unsigned short)s) << 16;
  return __uint_as_float(u);
}

#define GLOAD_LDS16(gp, lp)                                                          \
  __builtin_amdgcn_global_load_lds(                                                  \
      (const __attribute__((address_space(1))) unsigned int*)(gp),                   \
      (__attribute__((address_space(3))) unsigned int*)(lp), 16, 0, 0)

// ---------------- convert x (fp32 -> bf16) ----------------
__global__ void convert_x_kernel(const float* __restrict__ x, short* __restrict__ xb, int n8) {
  int i = blockIdx.x * blockDim.x + threadIdx.x;
  int stride = gridDim.x * blockDim.x;
  for (; i < n8; i += stride) {
    const fx4* p = (const fx4*)(x + (long)i * 8);
    fx4 a = p[0], b = p[1];
    sx8 o;
    o[0] = f2bf(a[0]); o[1] = f2bf(a[1]); o[2] = f2bf(a[2]); o[3] = f2bf(a[3]);
    o[4] = f2bf(b[0]); o[5] = f2bf(b[1]); o[6] = f2bf(b[2]); o[7] = f2bf(b[3]);
    *(sx8*)(xb + (long)i * 8) = o;
  }
}

// ------------- transpose weights to (N x K) bf16, zero-pad rows -------------
// dst[j][k] = bf16(src[k][col_off + j]) for j < valid_rows else 0.  dst is dst_rows x 1024.
__global__ void transpose_w_kernel(const float* __restrict__ src, short* __restrict__ dst,
                                   int src_cols, int col_off, int valid_rows) {
  __shared__ float t[32][33];
  int j0 = blockIdx.x * 32;
  int k0 = blockIdx.y * 32;
  int c = threadIdx.x & 31;
  int r = threadIdx.x >> 5;  // 0..7
#pragma unroll
  for (int i = 0; i < 4; i++) {
    int k = k0 + r + i * 8;
    int j = j0 + c;
    float v = (j < valid_rows) ? src[(long)k * src_cols + col_off + j] : 0.f;
    t[r + i * 8][c] = v;
  }
  __syncthreads();
#pragma unroll
  for (int i = 0; i < 4; i++) {
    int j = j0 + r + i * 8;
    dst[(long)j * 1024 + k0 + c] = f2bf(t[c][r + i * 8]);
  }
}

// ---------------- shared GEMM main loop (128x128 tile, bf16 MFMA) ----------------
__device__ __forceinline__ void gemm_mainloop(const short* __restrict__ A,
                                              const short* __restrict__ Bt,
                                              int m0, int n0,
                                              short* Ash, short* Bsh,
                                              fx4 acc[4][4]) {
  const int tid = threadIdx.x;
  const int lane = tid & 63;
  const int wave = tid >> 6;
  const int wm = wave >> 1, wn = wave & 1;

#pragma unroll
  for (int i = 0; i < 4; i++)
#pragma unroll
    for (int j = 0; j < 4; j++) acc[i][j] = fx4{0.f, 0.f, 0.f, 0.f};

  // staging: chunk j covers LDS elements [j*8, j*8+8) = tile (row j>>2, col (j&3)*8)
  const int j0 = wave * 64 + lane;
  const int j1 = 256 + j0;
  const short* a0 = A + (m0 + (j0 >> 2)) * KDIM + (j0 & 3) * 8;
  const short* a1 = A + (m0 + (j1 >> 2)) * KDIM + (j1 & 3) * 8;
  const short* b0 = Bt + (n0 + (j0 >> 2)) * KDIM + (j0 & 3) * 8;
  const short* b1 = Bt + (n0 + (j1 >> 2)) * KDIM + (j1 & 3) * 8;
  short* ldsA0 = Ash + wave * 512;
  short* ldsA1 = Ash + 2048 + wave * 512;
  short* ldsB0 = Bsh + wave * 512;
  short* ldsB1 = Bsh + 2048 + wave * 512;

  const int ar = (wm * 64 + (lane & 15)) * BK + (lane >> 4) * 8;
  const int br = (wn * 64 + (lane & 15)) * BK + (lane >> 4) * 8;

  for (int k0 = 0; k0 < KDIM; k0 += BK) {
    __syncthreads();
    GLOAD_LDS16(a0 + k0, ldsA0);
    GLOAD_LDS16(a1 + k0, ldsA1);
    GLOAD_LDS16(b0 + k0, ldsB0);
    GLOAD_LDS16(b1 + k0, ldsB1);
    __syncthreads();
    sx8 af[4], bf[4];
#pragma unroll
    for (int i = 0; i < 4; i++) af[i] = *(const sx8*)(Ash + ar + i * 16 * BK);
#pragma unroll
    for (int j = 0; j < 4; j++) bf[j] = *(const sx8*)(Bsh + br + j * 16 * BK);
#pragma unroll
    for (int i = 0; i < 4; i++)
#pragma unroll
      for (int j = 0; j < 4; j++)
        acc[i][j] = __builtin_amdgcn_mfma_f32_16x16x32_bf16(af[i], bf[j], acc[i][j], 0, 0, 0);
  }
}

// ---------------- GEMM1: xz = x @ W_in[:,1024:] + b_in[1024:], fused epilogue ---------------
__global__ __launch_bounds__(256, 2) void gemm1_kernel(
    const short* __restrict__ xb, const short* __restrict__ Wt1,
    const float* __restrict__ b_in, const float* __restrict__ A_log,
    short* __restrict__ g, float* __restrict__ Bb, float* __restrict__ Cb,
    float* __restrict__ ab) {
  __shared__ short Ash[BM * BK] __attribute__((aligned(16)));
  __shared__ short Bsh[BN * BK] __attribute__((aligned(16)));
  const int m0 = blockIdx.x * BM;
  const int n0 = blockIdx.y * BN;
  fx4 acc[4][4];
  gemm_mainloop(xb, Wt1, m0, n0, Ash, Bsh, acc);

  const int lane = threadIdx.x & 63;
  const int wave = threadIdx.x >> 6;
  const int wm = wave >> 1, wn = wave & 1;

#pragma unroll
  for (int j = 0; j < 4; j++) {
    int n = n0 + wn * 64 + j * 16 + (lane & 15);
    if (n >= N1) continue;
    float bias = b_in[1024 + n];
#pragma unroll
    for (int i = 0; i < 4; i++) {
#pragma unroll
      for (int r = 0; r < 4; r++) {
        int m = m0 + wm * 64 + i * 16 + (lane >> 4) * 4 + r;
        float v = acc[i][j][r] + bias;
        if (n < 1024) {
          float gl = 0.5f * v * (1.f + erff(v * 0.70710678118654752f));
          g[(long)m * 1024 + n] = f2bf(gl);
        } else if (n < 1040) {
          Bb[m * NSTATE + (n - 1024)] = v;
        } else if (n < 1056) {
          Cb[m * NSTATE + (n - 1040)] = v;
        } else {
          int c = n - 1056;
          float dlt = (v > 20.f) ? v : log1pf(expf(v));
          float Ac = -expf(A_log[c]);
          ab[m * NSTATE + c] = expf(Ac * dlt);
        }
      }
    }
  }
}

// ---------------- selective scan: 1 block per batch, lanes 0..15 = channels ----------------
__global__ void scan_kernel(const float* __restrict__ ab, const float* __restrict__ Bb,
                            const float* __restrict__ Cb, float* __restrict__ y) {
  int b = blockIdx.x;
  int ln = threadIdx.x & 15;
  int base = b * SEQ_LEN * NSTATE;
  float s = 0.f;
  for (int t0 = 0; t0 < SEQ_LEN; t0 += 8) {
    float av[8], bv[8], cv[8];
#pragma unroll
    for (int u = 0; u < 8; u++) {
      int idx = base + (t0 + u) * NSTATE + ln;
      av[u] = ab[idx];
      bv[u] = Bb[idx];
      cv[u] = Cb[idx];
    }
    float yr[8];
#pragma unroll
    for (int u = 0; u < 8; u++) {
      s = fmaf(av[u], s, bv[u]);
      float p = s * cv[u];
      p += __shfl_xor(p, 1);
      p += __shfl_xor(p, 2);
      p += __shfl_xor(p, 4);
      p += __shfl_xor(p, 8);
      yr[u] = p;
    }
    if (threadIdx.x == 0) {
#pragma unroll
      for (int u = 0; u < 8; u++) y[b * SEQ_LEN + t0 + u] = yr[u];
    }
  }
}

// ---------------- GEMM2: out = (y ⊙row g) @ W_out + b_out ----------------
__global__ __launch_bounds__(256, 2) void gemm2_kernel(
    const short* __restrict__ g, const short* __restrict__ Wt2,
    const float* __restrict__ y, const float* __restrict__ b_out,
    float* __restrict__ out) {
  __shared__ short Ash[BM * BK] __attribute__((aligned(16)));
  __shared__ short Bsh[BN * BK] __attribute__((aligned(16)));
  const int m0 = blockIdx.x * BM;
  const int n0 = blockIdx.y * BN;
  fx4 acc[4][4];
  gemm_mainloop(g, Wt2, m0, n0, Ash, Bsh, acc);

  const int lane = threadIdx.x & 63;
  const int wave = threadIdx.x >> 6;
  const int wm = wave >> 1, wn = wave & 1;

#pragma unroll
  for (int i = 0; i < 4; i++) {
#pragma unroll
    for (int r = 0; r < 4; r++) {
      int m = m0 + wm * 64 + i * 16 + (lane >> 4) * 4 + r;
      float ym = y[m];
#pragma unroll
      for (int j = 0; j < 4; j++) {
        int n = n0 + wn * 64 + j * 16 + (lane & 15);
        out[(long)m * 1024 + n] = fmaf(ym, acc[i][j][r], b_out[n]);
      }
    }
  }
}

extern "C" void kernel_launch(void* const* d_in, const int* in_sizes, int n_in,
                              void* d_out, int out_size, void* d_ws, size_t ws_size,
                              hipStream_t stream) {
  const float* x     = (const float*)d_in[0];
  const float* W_in  = (const float*)d_in[1];
  const float* b_in  = (const float*)d_in[2];
  const float* A_log = (const float*)d_in[3];
  const float* W_out = (const float*)d_in[4];
  const float* b_out = (const float*)d_in[5];
  float* out = (float*)d_out;

  char* ws = (char*)d_ws;
  short* xb = (short*)ws;  ws += (size_t)MROWS * KDIM * 2;       // 134.2 MB
  short* g  = (short*)ws;  ws += (size_t)MROWS * KDIM * 2;       // 134.2 MB
  short* Wt1 = (short*)ws; ws += (size_t)N1PAD * KDIM * 2;       // 2.36 MB
  short* Wt2 = (short*)ws; ws += (size_t)KDIM * KDIM * 2;        // 2.10 MB
  float* Bb = (float*)ws;  ws += (size_t)MROWS * NSTATE * 4;     // 4.19 MB
  float* Cb = (float*)ws;  ws += (size_t)MROWS * NSTATE * 4;
  float* ab = (float*)ws;  ws += (size_t)MROWS * NSTATE * 4;
  float* y  = (float*)ws;  ws += (size_t)MROWS * 4;

  convert_x_kernel<<<4096, 256, 0, stream>>>(x, xb, MROWS * KDIM / 8);
  transpose_w_kernel<<<dim3(N1PAD / 32, 32), 256, 0, stream>>>(W_in, Wt1, 2096, 1024, N1);
  transpose_w_kernel<<<dim3(32, 32), 256, 0, stream>>>(W_out, Wt2, 1024, 0, 1024);
  gemm1_kernel<<<dim3(MROWS / BM, N1PAD / BN), 256, 0, stream>>>(xb, Wt1, b_in, A_log, g, Bb, Cb, ab);
  scan_kernel<<<NBATCH, 64, 0, stream>>>(ab, Bb, Cb, y);
  gemm2_kernel<<<dim3(MROWS / BM, KDIM / BN), 256, 0, stream>>>(g, Wt2, y, b_out, out);
}

// Round 3
// 748.862 us; speedup vs baseline: 1.0108x; 1.0108x over previous
//
#include <hip/hip_runtime.h>
#include <cstdint>

typedef float fx4 __attribute__((ext_vector_type(4)));
typedef short sx8 __attribute__((ext_vector_type(8)));

#define NSTATE 16
#define SEQ_LEN 2048
#define NBATCH 32
#define MROWS 65536           // NBATCH*SEQ_LEN
#define KDIM 1024
#define N1 1072               // z(1024) + B(16) + C(16) + delta(16)
#define N1PAD 1152            // 9 tiles of 128
#define BM 128
#define BN 128
#define BK 32

__device__ __forceinline__ short f2bf(float f) {
  unsigned u = __float_as_uint(f);
  u += 0x7FFFu + ((u >> 16) & 1u);   // round-to-nearest-even
  return (short)(u >> 16);
}

#define GLOAD_LDS16(gp, lp)                                                          \
  __builtin_amdgcn_global_load_lds(                                                  \
      (const __attribute__((address_space(1))) unsigned int*)(gp),                   \
      (__attribute__((address_space(3))) unsigned int*)(lp), 16, 0, 0)

// ---------------- convert x (fp32 -> bf16) ----------------
__global__ void convert_x_kernel(const float* __restrict__ x, short* __restrict__ xb, int n8) {
  int i = blockIdx.x * blockDim.x + threadIdx.x;
  int stride = gridDim.x * blockDim.x;
  for (; i < n8; i += stride) {
    const fx4* p = (const fx4*)(x + (long)i * 8);
    fx4 a = p[0], b = p[1];
    sx8 o;
    o[0] = f2bf(a[0]); o[1] = f2bf(a[1]); o[2] = f2bf(a[2]); o[3] = f2bf(a[3]);
    o[4] = f2bf(b[0]); o[5] = f2bf(b[1]); o[6] = f2bf(b[2]); o[7] = f2bf(b[3]);
    *(sx8*)(xb + (long)i * 8) = o;
  }
}

// ------------- transpose weights to (N x K) bf16, zero-pad rows -------------
__global__ void transpose_w_kernel(const float* __restrict__ src, short* __restrict__ dst,
                                   int src_cols, int col_off, int valid_rows) {
  __shared__ float t[32][33];
  int j0 = blockIdx.x * 32;
  int k0 = blockIdx.y * 32;
  int c = threadIdx.x & 31;
  int r = threadIdx.x >> 5;  // 0..7
#pragma unroll
  for (int i = 0; i < 4; i++) {
    int k = k0 + r + i * 8;
    int j = j0 + c;
    float v = (j < valid_rows) ? src[(long)k * src_cols + col_off + j] : 0.f;
    t[r + i * 8][c] = v;
  }
  __syncthreads();
#pragma unroll
  for (int i = 0; i < 4; i++) {
    int j = j0 + r + i * 8;
    dst[(long)j * 1024 + k0 + c] = f2bf(t[c][r + i * 8]);
  }
}

// ------------- shared GEMM main loop: 128x128 tile, double-buffered LDS, counted vmcnt -------------
__device__ __forceinline__ void gemm_mainloop(const short* __restrict__ A,
                                              const short* __restrict__ Bt,
                                              int m0, int n0,
                                              short* AshD, short* BshD,
                                              fx4 acc[4][4]) {
  const int tid = threadIdx.x;
  const int lane = tid & 63;
  const int wave = tid >> 6;
  const int wm = wave >> 1, wn = wave & 1;

#pragma unroll
  for (int i = 0; i < 4; i++)
#pragma unroll
    for (int j = 0; j < 4; j++) acc[i][j] = fx4{0.f, 0.f, 0.f, 0.f};

  // staging: chunk j covers LDS shorts [j*8, j*8+8) = tile (row j>>2, slot j&3)
  const int j0 = wave * 64 + lane;
  const int j1 = 256 + j0;
  const short* a0 = A + (m0 + (j0 >> 2)) * KDIM + (j0 & 3) * 8;
  const short* a1 = A + (m0 + (j1 >> 2)) * KDIM + (j1 & 3) * 8;
  const short* b0 = Bt + (n0 + (j0 >> 2)) * KDIM + (j0 & 3) * 8;
  const short* b1 = Bt + (n0 + (j1 >> 2)) * KDIM + (j1 & 3) * 8;
  const int woff = wave * 512;

  const int ar = (wm * 64 + (lane & 15)) * BK + (lane >> 4) * 8;
  const int br = (wn * 64 + (lane & 15)) * BK + (lane >> 4) * 8;

  // prologue: stage k=0 into buffer 0
  GLOAD_LDS16(a0, AshD + woff);
  GLOAD_LDS16(a1, AshD + 2048 + woff);
  GLOAD_LDS16(b0, BshD + woff);
  GLOAD_LDS16(b1, BshD + 2048 + woff);

  int cur = 0;
  for (int k0 = 0; k0 < KDIM; k0 += BK) {
    const int nb = (cur ^ 1) * 4096;
    if (k0 + BK < KDIM) {
      // prefetch next K-tile into the other buffer (stays in flight across the barrier)
      GLOAD_LDS16(a0 + k0 + BK, AshD + nb + woff);
      GLOAD_LDS16(a1 + k0 + BK, AshD + nb + 2048 + woff);
      GLOAD_LDS16(b0 + k0 + BK, BshD + nb + woff);
      GLOAD_LDS16(b1 + k0 + BK, BshD + nb + 2048 + woff);
      asm volatile("s_waitcnt vmcnt(4)" ::: "memory");  // wait only current tile's loads
    } else {
      asm volatile("s_waitcnt vmcnt(0)" ::: "memory");
    }
    __builtin_amdgcn_s_barrier();          // current buffer now valid for all waves
    asm volatile("" ::: "memory");         // fence: keep ds_reads below the barrier

    const short* As = AshD + cur * 4096;
    const short* Bs = BshD + cur * 4096;
    sx8 af[4], bfr[4];
#pragma unroll
    for (int i = 0; i < 4; i++) af[i] = *(const sx8*)(As + ar + i * 16 * BK);
#pragma unroll
    for (int j = 0; j < 4; j++) bfr[j] = *(const sx8*)(Bs + br + j * 16 * BK);
#pragma unroll
    for (int i = 0; i < 4; i++)
#pragma unroll
      for (int j = 0; j < 4; j++)
        acc[i][j] = __builtin_amdgcn_mfma_f32_16x16x32_bf16(af[i], bfr[j], acc[i][j], 0, 0, 0);

    asm volatile("s_waitcnt lgkmcnt(0)" ::: "memory");  // this wave's ds_reads landed
    __builtin_amdgcn_s_barrier();          // all waves done reading -> safe to overwrite next iter
    asm volatile("" ::: "memory");
    cur ^= 1;
  }
}

// ---------------- GEMM1: xz = x @ W_in[:,1024:] + b_in[1024:], fused epilogue ---------------
__global__ __launch_bounds__(256, 3) void gemm1_kernel(
    const short* __restrict__ xb, const short* __restrict__ Wt1,
    const float* __restrict__ b_in, const float* __restrict__ A_log,
    short* __restrict__ g, float* __restrict__ Bb, float* __restrict__ Cb,
    float* __restrict__ ab) {
  __shared__ short Ash[2 * BM * BK] __attribute__((aligned(16)));
  __shared__ short Bsh[2 * BN * BK] __attribute__((aligned(16)));
  // bijective XCD swizzle + N-inner order: each XCD owns 64 contiguous M-tiles x all 9 N-tiles
  const int bid = blockIdx.x;                 // 0..4607
  const int wgid = (bid & 7) * 576 + (bid >> 3);
  const int nt = wgid % 9;
  const int mt = wgid / 9;
  const int m0 = mt * BM;
  const int n0 = nt * BN;
  fx4 acc[4][4];
  gemm_mainloop(xb, Wt1, m0, n0, Ash, Bsh, acc);

  const int lane = threadIdx.x & 63;
  const int wave = threadIdx.x >> 6;
  const int wm = wave >> 1, wn = wave & 1;

#pragma unroll
  for (int j = 0; j < 4; j++) {
    int n = n0 + wn * 64 + j * 16 + (lane & 15);
    if (n >= N1) continue;
    float bias = b_in[1024 + n];
#pragma unroll
    for (int i = 0; i < 4; i++) {
#pragma unroll
      for (int r = 0; r < 4; r++) {
        int m = m0 + wm * 64 + i * 16 + (lane >> 4) * 4 + r;
        float v = acc[i][j][r] + bias;
        if (n < 1024) {
          float gl = 0.5f * v * (1.f + erff(v * 0.70710678118654752f));
          g[(long)m * 1024 + n] = f2bf(gl);
        } else if (n < 1040) {
          Bb[m * NSTATE + (n - 1024)] = v;
        } else if (n < 1056) {
          Cb[m * NSTATE + (n - 1040)] = v;
        } else {
          int c = n - 1056;
          float dlt = (v > 20.f) ? v : log1pf(expf(v));
          float Ac = -expf(A_log[c]);
          ab[m * NSTATE + c] = expf(Ac * dlt);
        }
      }
    }
  }
}

// ---------------- selective scan: 1 block per batch, lanes 0..15 = channels ----------------
__global__ void scan_kernel(const float* __restrict__ ab, const float* __restrict__ Bb,
                            const float* __restrict__ Cb, float* __restrict__ y) {
  int b = blockIdx.x;
  int ln = threadIdx.x & 15;
  int base = b * SEQ_LEN * NSTATE;
  float s = 0.f;
  for (int t0 = 0; t0 < SEQ_LEN; t0 += 8) {
    float av[8], bv[8], cv[8];
#pragma unroll
    for (int u = 0; u < 8; u++) {
      int idx = base + (t0 + u) * NSTATE + ln;
      av[u] = ab[idx];
      bv[u] = Bb[idx];
      cv[u] = Cb[idx];
    }
    float yr[8];
#pragma unroll
    for (int u = 0; u < 8; u++) {
      s = fmaf(av[u], s, bv[u]);
      float p = s * cv[u];
      p += __shfl_xor(p, 1);
      p += __shfl_xor(p, 2);
      p += __shfl_xor(p, 4);
      p += __shfl_xor(p, 8);
      yr[u] = p;
    }
    if (threadIdx.x == 0) {
#pragma unroll
      for (int u = 0; u < 8; u++) y[b * SEQ_LEN + t0 + u] = yr[u];
    }
  }
}

// ---------------- GEMM2: out = (y ⊙row g) @ W_out + b_out ----------------
__global__ __launch_bounds__(256, 3) void gemm2_kernel(
    const short* __restrict__ g, const short* __restrict__ Wt2,
    const float* __restrict__ y, const float* __restrict__ b_out,
    float* __restrict__ out) {
  __shared__ short Ash[2 * BM * BK] __attribute__((aligned(16)));
  __shared__ short Bsh[2 * BN * BK] __attribute__((aligned(16)));
  const int bid = blockIdx.x;                 // 0..4095
  const int wgid = (bid & 7) * 512 + (bid >> 3);
  const int nt = wgid & 7;
  const int mt = wgid >> 3;
  const int m0 = mt * BM;
  const int n0 = nt * BN;
  fx4 acc[4][4];
  gemm_mainloop(g, Wt2, m0, n0, Ash, Bsh, acc);

  const int lane = threadIdx.x & 63;
  const int wave = threadIdx.x >> 6;
  const int wm = wave >> 1, wn = wave & 1;

#pragma unroll
  for (int i = 0; i < 4; i++) {
#pragma unroll
    for (int r = 0; r < 4; r++) {
      int m = m0 + wm * 64 + i * 16 + (lane >> 4) * 4 + r;
      float ym = y[m];
#pragma unroll
      for (int j = 0; j < 4; j++) {
        int n = n0 + wn * 64 + j * 16 + (lane & 15);
        out[(long)m * 1024 + n] = fmaf(ym, acc[i][j][r], b_out[n]);
      }
    }
  }
}

extern "C" void kernel_launch(void* const* d_in, const int* in_sizes, int n_in,
                              void* d_out, int out_size, void* d_ws, size_t ws_size,
                              hipStream_t stream) {
  const float* x     = (const float*)d_in[0];
  const float* W_in  = (const float*)d_in[1];
  const float* b_in  = (const float*)d_in[2];
  const float* A_log = (const float*)d_in[3];
  const float* W_out = (const float*)d_in[4];
  const float* b_out = (const float*)d_in[5];
  float* out = (float*)d_out;

  char* ws = (char*)d_ws;
  short* xb = (short*)ws;  ws += (size_t)MROWS * KDIM * 2;       // 134.2 MB
  short* g  = (short*)ws;  ws += (size_t)MROWS * KDIM * 2;       // 134.2 MB
  short* Wt1 = (short*)ws; ws += (size_t)N1PAD * KDIM * 2;       // 2.36 MB
  short* Wt2 = (short*)ws; ws += (size_t)KDIM * KDIM * 2;        // 2.10 MB
  float* Bb = (float*)ws;  ws += (size_t)MROWS * NSTATE * 4;     // 4.19 MB
  float* Cb = (float*)ws;  ws += (size_t)MROWS * NSTATE * 4;
  float* ab = (float*)ws;  ws += (size_t)MROWS * NSTATE * 4;
  float* y  = (float*)ws;  ws += (size_t)MROWS * 4;

  convert_x_kernel<<<4096, 256, 0, stream>>>(x, xb, MROWS * KDIM / 8);
  transpose_w_kernel<<<dim3(N1PAD / 32, 32), 256, 0, stream>>>(W_in, Wt1, 2096, 1024, N1);
  transpose_w_kernel<<<dim3(32, 32), 256, 0, stream>>>(W_out, Wt2, 1024, 0, 1024);
  gemm1_kernel<<<MROWS / BM * (N1PAD / BN), 256, 0, stream>>>(xb, Wt1, b_in, A_log, g, Bb, Cb, ab);
  scan_kernel<<<NBATCH, 64, 0, stream>>>(ab, Bb, Cb, y);
  gemm2_kernel<<<MROWS / BM * (KDIM / BN), 256, 0, stream>>>(g, Wt2, y, b_out, out);
}

// Round 4
// 708.533 us; speedup vs baseline: 1.0683x; 1.0569x over previous
//
#include <hip/hip_runtime.h>
#include <cstdint>

typedef float fx4 __attribute__((ext_vector_type(4)));
typedef short sx8 __attribute__((ext_vector_type(8)));

#define NSTATE 16
#define SEQ_LEN 2048
#define NBATCH 32
#define MROWS 65536           // NBATCH*SEQ_LEN
#define KDIM 1024
#define N1 1072               // z(1024) + B(16) + C(16) + delta(16)
#define N1PAD 1280            // 5 tiles of 256
#define BM 256
#define BN 256
#define BK2 32
#define NT (KDIM / BK2)       // 32 K-tiles
#define LDS_SHORTS (3 * 2 * BM * BK2)   // 3 buffers x (A 8192 + B 8192) shorts = 96KB

__device__ __forceinline__ short f2bf(float f) {
  unsigned u = __float_as_uint(f);
  u += 0x7FFFu + ((u >> 16) & 1u);   // round-to-nearest-even
  return (short)(u >> 16);
}

#define GLOAD_LDS16(gp, lp)                                                          \
  __builtin_amdgcn_global_load_lds(                                                  \
      (const __attribute__((address_space(1))) unsigned int*)(gp),                   \
      (__attribute__((address_space(3))) unsigned int*)(lp), 16, 0, 0)

// ---------------- convert x (fp32 -> bf16) ----------------
__global__ void convert_x_kernel(const float* __restrict__ x, short* __restrict__ xb, int n8) {
  int i = blockIdx.x * blockDim.x + threadIdx.x;
  int stride = gridDim.x * blockDim.x;
  for (; i < n8; i += stride) {
    const fx4* p = (const fx4*)(x + (long)i * 8);
    fx4 a = p[0], b = p[1];
    sx8 o;
    o[0] = f2bf(a[0]); o[1] = f2bf(a[1]); o[2] = f2bf(a[2]); o[3] = f2bf(a[3]);
    o[4] = f2bf(b[0]); o[5] = f2bf(b[1]); o[6] = f2bf(b[2]); o[7] = f2bf(b[3]);
    *(sx8*)(xb + (long)i * 8) = o;
  }
}

// ------------- transpose weights to (N x K) bf16, zero-pad rows -------------
__global__ void transpose_w_kernel(const float* __restrict__ src, short* __restrict__ dst,
                                   int src_cols, int col_off, int valid_rows) {
  __shared__ float t[32][33];
  int j0 = blockIdx.x * 32;
  int k0 = blockIdx.y * 32;
  int c = threadIdx.x & 31;
  int r = threadIdx.x >> 5;  // 0..7
#pragma unroll
  for (int i = 0; i < 4; i++) {
    int k = k0 + r + i * 8;
    int j = j0 + c;
    float v = (j < valid_rows) ? src[(long)k * src_cols + col_off + j] : 0.f;
    t[r + i * 8][c] = v;
  }
  __syncthreads();
#pragma unroll
  for (int i = 0; i < 4; i++) {
    int j = j0 + r + i * 8;
    dst[(long)j * 1024 + k0 + c] = f2bf(t[c][r + i * 8]);
  }
}

// stage one 256x32 bf16 tile (16KB): 512 threads x 2 x 16B. Swizzle: physical slot sp
// holds logical kslot sp ^ ((r>>1)&3)  (inverse-swizzled global source, linear LDS dest).
__device__ __forceinline__ void stage_tile(const short* __restrict__ src, int row0, int kt,
                                           short* ldsT, int tid) {
#pragma unroll
  for (int c = 0; c < 2; c++) {
    int L = c * 512 + tid;
    int r = L >> 2, sp = L & 3;
    int kslot = sp ^ ((r >> 1) & 3);
    const short* gp = src + (long)(row0 + r) * KDIM + kt * BK2 + kslot * 8;
    GLOAD_LDS16(gp, ldsT + L * 8);
  }
}

// ---- 256x256 phase-split mainloop: 3-buffer rotation, counted vmcnt, setprio ----
__device__ __forceinline__ void gemm_mainloop256(const short* __restrict__ A,
                                                 const short* __restrict__ Bt,
                                                 int m0, int n0, short* lds,
                                                 fx4 acc[8][4]) {
  const int tid = threadIdx.x;
  const int lane = tid & 63;
  const int wave = tid >> 6;
  const int wm = wave >> 2, wn = wave & 3;   // 2 x 4 wave grid; wave output 128x64

#pragma unroll
  for (int i = 0; i < 8; i++)
#pragma unroll
    for (int j = 0; j < 4; j++) acc[i][j] = fx4{0.f, 0.f, 0.f, 0.f};

  const int ks = lane >> 4;                  // k-slot 0..3
  // per-frag LDS short offsets (swizzled)
  int aoff[8], boff[4];
#pragma unroll
  for (int mi = 0; mi < 8; mi++) {
    int rr = wm * 128 + mi * 16 + (lane & 15);
    aoff[mi] = rr * BK2 + (ks ^ ((rr >> 1) & 3)) * 8;
  }
#pragma unroll
  for (int ni = 0; ni < 4; ni++) {
    int rr = wn * 64 + ni * 16 + (lane & 15);
    boff[ni] = rr * BK2 + (ks ^ ((rr >> 1) & 3)) * 8;
  }

  // prologue: stage tiles 0 and 1
  stage_tile(A, m0, 0, lds, tid);
  stage_tile(Bt, n0, 0, lds + 8192, tid);
  stage_tile(A, m0, 1, lds + 16384, tid);
  stage_tile(Bt, n0, 1, lds + 16384 + 8192, tid);
  asm volatile("s_waitcnt vmcnt(4)\n\ts_barrier" ::: "memory");   // tile 0 staged

  for (int t = 0; t < NT; ++t) {
    const short* bufA = lds + (t % 3) * 16384;
    const short* bufB = bufA + 8192;
    short* stBuf = lds + ((t + 2) % 3) * 16384;
    const int ts = t + 2;

    // ---- phase A: read A-frags (8) + B-frags 0,1; stage A(t+2); MFMA nh=0 ----
    sx8 af[8], bf0, bf1;
#pragma unroll
    for (int mi = 0; mi < 8; mi++) af[mi] = *(const sx8*)(bufA + aoff[mi]);
    bf0 = *(const sx8*)(bufB + boff[0]);
    bf1 = *(const sx8*)(bufB + boff[1]);
    if (ts < NT) stage_tile(A, m0, ts, stBuf, tid);
    asm volatile("s_barrier" ::: "memory");
    __builtin_amdgcn_s_setprio(1);
#pragma unroll
    for (int mi = 0; mi < 8; mi++) {
      acc[mi][0] = __builtin_amdgcn_mfma_f32_16x16x32_bf16(af[mi], bf0, acc[mi][0], 0, 0, 0);
      acc[mi][1] = __builtin_amdgcn_mfma_f32_16x16x32_bf16(af[mi], bf1, acc[mi][1], 0, 0, 0);
    }
    __builtin_amdgcn_s_setprio(0);
    asm volatile("s_barrier" ::: "memory");

    // ---- phase B: read B-frags 2,3; stage B(t+2); MFMA nh=1 ----
    sx8 bf2 = *(const sx8*)(bufB + boff[2]);
    sx8 bf3 = *(const sx8*)(bufB + boff[3]);
    if (ts < NT) stage_tile(Bt, n0, ts, stBuf + 8192, tid);
    asm volatile("s_barrier" ::: "memory");
    __builtin_amdgcn_s_setprio(1);
#pragma unroll
    for (int mi = 0; mi < 8; mi++) {
      acc[mi][2] = __builtin_amdgcn_mfma_f32_16x16x32_bf16(af[mi], bf2, acc[mi][2], 0, 0, 0);
      acc[mi][3] = __builtin_amdgcn_mfma_f32_16x16x32_bf16(af[mi], bf3, acc[mi][3], 0, 0, 0);
    }
    __builtin_amdgcn_s_setprio(0);

    // ---- tile boundary: wait tile t+1's 4 loads; keep t+2's 4 in flight ----
    if (t < NT - 2) asm volatile("s_waitcnt vmcnt(4)\n\ts_barrier" ::: "memory");
    else            asm volatile("s_waitcnt vmcnt(0)\n\ts_barrier" ::: "memory");
  }
}

// ---------------- GEMM1: xz = x @ W_in[:,1024:] + b_in[1024:], fused epilogue ---------------
__global__ __launch_bounds__(512, 2) void gemm1_kernel(
    const short* __restrict__ xb, const short* __restrict__ Wt1,
    const float* __restrict__ b_in, const float* __restrict__ A_log,
    short* __restrict__ g, float* __restrict__ Bb, float* __restrict__ Cb,
    float* __restrict__ ab) {
  extern __shared__ short lds[];
  const int bid = blockIdx.x;                  // 0..1279
  const int wgid = (bid & 7) * 160 + (bid >> 3);
  const int nt = wgid % 5;
  const int mt = wgid / 5;
  const int m0 = mt * BM;
  const int n0 = nt * BN;
  fx4 acc[8][4];
  gemm_mainloop256(xb, Wt1, m0, n0, lds, acc);

  const int lane = threadIdx.x & 63;
  const int wave = threadIdx.x >> 6;
  const int wm = wave >> 2, wn = wave & 3;

#pragma unroll
  for (int ni = 0; ni < 4; ni++) {
    int n = n0 + wn * 64 + ni * 16 + (lane & 15);
    if (n >= N1) continue;
    float bias = b_in[1024 + n];
#pragma unroll
    for (int mi = 0; mi < 8; mi++) {
#pragma unroll
      for (int r = 0; r < 4; r++) {
        int m = m0 + wm * 128 + mi * 16 + (lane >> 4) * 4 + r;
        float v = acc[mi][ni][r] + bias;
        if (n < 1024) {
          float gl = 0.5f * v * (1.f + erff(v * 0.70710678118654752f));
          g[(long)m * 1024 + n] = f2bf(gl);
        } else if (n < 1040) {
          Bb[m * NSTATE + (n - 1024)] = v;
        } else if (n < 1056) {
          Cb[m * NSTATE + (n - 1040)] = v;
        } else {
          int c = n - 1056;
          float dlt = (v > 20.f) ? v : log1pf(expf(v));
          float Ac = -expf(A_log[c]);
          ab[m * NSTATE + c] = expf(Ac * dlt);
        }
      }
    }
  }
}

// ---- selective scan: serial chain is fma-only; products written per-channel ----
__global__ void scan_kernel(const float* __restrict__ ab, const float* __restrict__ Bb,
                            const float* __restrict__ Cb, float* __restrict__ p) {
  int b = blockIdx.x;
  int ln = threadIdx.x;
  if (ln >= NSTATE) return;
  const float* pa = ab + b * SEQ_LEN * NSTATE + ln;
  const float* pb = Bb + b * SEQ_LEN * NSTATE + ln;
  const float* pc = Cb + b * SEQ_LEN * NSTATE + ln;
  float* po = p + (long)b * SEQ_LEN * NSTATE + ln;
  float s = 0.f;
  float a0[8], b0[8], c0[8], a1[8], b1[8], c1[8];
#pragma unroll
  for (int u = 0; u < 8; u++) {
    int o = u * NSTATE;
    a0[u] = pa[o]; b0[u] = pb[o]; c0[u] = pc[o];
  }
  for (int t0 = 0; t0 < SEQ_LEN; t0 += 16) {
#pragma unroll
    for (int u = 0; u < 8; u++) {
      int o = (t0 + 8 + u) * NSTATE;
      a1[u] = pa[o]; b1[u] = pb[o]; c1[u] = pc[o];
    }
#pragma unroll
    for (int u = 0; u < 8; u++) {
      s = fmaf(a0[u], s, b0[u]);
      po[(t0 + u) * NSTATE] = s * c0[u];
    }
    if (t0 + 16 < SEQ_LEN) {
#pragma unroll
      for (int u = 0; u < 8; u++) {
        int o = (t0 + 16 + u) * NSTATE;
        a0[u] = pa[o]; b0[u] = pb[o]; c0[u] = pc[o];
      }
    }
#pragma unroll
    for (int u = 0; u < 8; u++) {
      s = fmaf(a1[u], s, b1[u]);
      po[(t0 + 8 + u) * NSTATE] = s * c1[u];
    }
  }
}

// ---------------- reduce p over 16 channels -> y ----------------
__global__ void reduce_y_kernel(const float* __restrict__ p, float* __restrict__ y) {
  int m = blockIdx.x * blockDim.x + threadIdx.x;
  const fx4* row = (const fx4*)(p + (long)m * NSTATE);
  fx4 v = row[0] + row[1] + row[2] + row[3];
  y[m] = v[0] + v[1] + v[2] + v[3];
}

// ---------------- GEMM2: out = (y ⊙row g) @ W_out + b_out ----------------
__global__ __launch_bounds__(512, 2) void gemm2_kernel(
    const short* __restrict__ g, const short* __restrict__ Wt2,
    const float* __restrict__ y, const float* __restrict__ b_out,
    float* __restrict__ out) {
  extern __shared__ short lds[];
  const int bid = blockIdx.x;                  // 0..1023
  const int wgid = (bid & 7) * 128 + (bid >> 3);
  const int nt = wgid & 3;
  const int mt = wgid >> 2;
  const int m0 = mt * BM;
  const int n0 = nt * BN;
  fx4 acc[8][4];
  gemm_mainloop256(g, Wt2, m0, n0, lds, acc);

  const int lane = threadIdx.x & 63;
  const int wave = threadIdx.x >> 6;
  const int wm = wave >> 2, wn = wave & 3;

#pragma unroll
  for (int mi = 0; mi < 8; mi++) {
#pragma unroll
    for (int r = 0; r < 4; r++) {
      int m = m0 + wm * 128 + mi * 16 + (lane >> 4) * 4 + r;
      float ym = y[m];
#pragma unroll
      for (int ni = 0; ni < 4; ni++) {
        int n = n0 + wn * 64 + ni * 16 + (lane & 15);
        out[(long)m * 1024 + n] = fmaf(ym, acc[mi][ni][r], b_out[n]);
      }
    }
  }
}

extern "C" void kernel_launch(void* const* d_in, const int* in_sizes, int n_in,
                              void* d_out, int out_size, void* d_ws, size_t ws_size,
                              hipStream_t stream) {
  const float* x     = (const float*)d_in[0];
  const float* W_in  = (const float*)d_in[1];
  const float* b_in  = (const float*)d_in[2];
  const float* A_log = (const float*)d_in[3];
  const float* W_out = (const float*)d_in[4];
  const float* b_out = (const float*)d_in[5];
  float* out = (float*)d_out;

  char* ws = (char*)d_ws;
  short* xb = (short*)ws;  ws += (size_t)MROWS * KDIM * 2;       // 134.2 MB
  short* g  = (short*)ws;  ws += (size_t)MROWS * KDIM * 2;       // 134.2 MB
  short* Wt1 = (short*)ws; ws += (size_t)N1PAD * KDIM * 2;       // 2.6 MB
  short* Wt2 = (short*)ws; ws += (size_t)KDIM * KDIM * 2;        // 2.1 MB
  float* Bb = (float*)ws;  ws += (size_t)MROWS * NSTATE * 4;     // 4.19 MB
  float* Cb = (float*)ws;  ws += (size_t)MROWS * NSTATE * 4;
  float* ab = (float*)ws;  ws += (size_t)MROWS * NSTATE * 4;
  float* p  = (float*)ws;  ws += (size_t)MROWS * NSTATE * 4;
  float* y  = (float*)ws;  ws += (size_t)MROWS * 4;

  convert_x_kernel<<<4096, 256, 0, stream>>>(x, xb, MROWS * KDIM / 8);
  transpose_w_kernel<<<dim3(N1PAD / 32, 32), 256, 0, stream>>>(W_in, Wt1, 2096, 1024, N1);
  transpose_w_kernel<<<dim3(32, 32), 256, 0, stream>>>(W_out, Wt2, 1024, 0, 1024);
  gemm1_kernel<<<MROWS / BM * (N1PAD / BN), 512, LDS_SHORTS * 2, stream>>>(
      xb, Wt1, b_in, A_log, g, Bb, Cb, ab);
  scan_kernel<<<NBATCH, 64, 0, stream>>>(ab, Bb, Cb, p);
  reduce_y_kernel<<<MROWS / 256, 256, 0, stream>>>(p, y);
  gemm2_kernel<<<MROWS / BM * (KDIM / BN), 512, LDS_SHORTS * 2, stream>>>(
      g, Wt2, y, b_out, out);
}

// Round 5
// 682.628 us; speedup vs baseline: 1.1088x; 1.0379x over previous
//
#include <hip/hip_runtime.h>
#include <cstdint>

typedef float fx4 __attribute__((ext_vector_type(4)));
typedef short sx8 __attribute__((ext_vector_type(8)));

#define NSTATE 16
#define SEQ_LEN 2048
#define NBATCH 32
#define MROWS 65536           // NBATCH*SEQ_LEN
#define KDIM 1024
#define N1 1072               // z(1024) + B(16) + C(16) + delta(16)
#define N1PAD 1280            // 5 tiles of 256
#define BM 256
#define BN 256
#define BK 64
#define NT (KDIM / BK)        // 16 K-tiles
// LDS: 2 dbuf x (A 256x64 + B 256x64) bf16 = 2 x 64KB = 128KB
#define DBUF_SHORTS 32768
#define AH1 8192
#define BH0 16384
#define BH1 24576

__device__ __forceinline__ short f2bf(float f) {
  unsigned u = __float_as_uint(f);
  u += 0x7FFFu + ((u >> 16) & 1u);   // round-to-nearest-even
  return (short)(u >> 16);
}

#define GLOAD_LDS16(gp, lp)                                                          \
  __builtin_amdgcn_global_load_lds(                                                  \
      (const __attribute__((address_space(1))) unsigned int*)(gp),                   \
      (__attribute__((address_space(3))) unsigned int*)(lp), 16, 0, 0)

#define SBAR()   asm volatile("s_barrier" ::: "memory")
#define WAITLGKM() asm volatile("s_waitcnt lgkmcnt(0)" ::: "memory")
#define WAITVM(n)  asm volatile("s_waitcnt vmcnt(" #n ")" ::: "memory")

// ---------------- convert x (fp32 -> bf16) ----------------
__global__ void convert_x_kernel(const float* __restrict__ x, short* __restrict__ xb, int n8) {
  int i = blockIdx.x * blockDim.x + threadIdx.x;
  int stride = gridDim.x * blockDim.x;
  for (; i < n8; i += stride) {
    const fx4* p = (const fx4*)(x + (long)i * 8);
    fx4 a = p[0], b = p[1];
    sx8 o;
    o[0] = f2bf(a[0]); o[1] = f2bf(a[1]); o[2] = f2bf(a[2]); o[3] = f2bf(a[3]);
    o[4] = f2bf(b[0]); o[5] = f2bf(b[1]); o[6] = f2bf(b[2]); o[7] = f2bf(b[3]);
    *(sx8*)(xb + (long)i * 8) = o;
  }
}

// ------------- transpose weights to (N x K) bf16, zero-pad rows -------------
__global__ void transpose_w_kernel(const float* __restrict__ src, short* __restrict__ dst,
                                   int src_cols, int col_off, int valid_rows) {
  __shared__ float t[32][33];
  int j0 = blockIdx.x * 32;
  int k0 = blockIdx.y * 32;
  int c = threadIdx.x & 31;
  int r = threadIdx.x >> 5;  // 0..7
#pragma unroll
  for (int i = 0; i < 4; i++) {
    int k = k0 + r + i * 8;
    int j = j0 + c;
    float v = (j < valid_rows) ? src[(long)k * src_cols + col_off + j] : 0.f;
    t[r + i * 8][c] = v;
  }
  __syncthreads();
#pragma unroll
  for (int i = 0; i < 4; i++) {
    int j = j0 + r + i * 8;
    dst[(long)j * 1024 + k0 + c] = f2bf(t[c][r + i * 8]);
  }
}

// stage one 128x64 bf16 half-tile (16KB): 512 thr x 2 x 16B, linear LDS dest.
// LDS row r physical slot p holds logical k-slot q=(p-r)&7  (rotation swizzle,
// inverse applied on the global source; read side uses p=(s+r)&7).  2-way banks.
__device__ __forceinline__ void stage_half(const short* __restrict__ src, int row0, int kt,
                                           short* dst, int tid) {
#pragma unroll
  for (int c = 0; c < 2; c++) {
    int L = c * 512 + tid;           // 16B units, 0..1023
    int r = L >> 3, p = L & 7;
    int q = (p - r) & 7;
    const short* gp = src + (long)(row0 + r) * KDIM + kt * BK + q * 8;
    GLOAD_LDS16(gp, dst + L * 8);
  }
}

// ---- 256x256 mainloop: BK=64, 4 phases/K-tile, counted vmcnt(4), setprio ----
__device__ __forceinline__ void gemm_mainloop256(const short* __restrict__ A,
                                                 const short* __restrict__ Bt,
                                                 int m0, int n0, short* lds,
                                                 fx4 acc[8][4]) {
  const int tid = threadIdx.x;
  const int lane = tid & 63;
  const int wave = tid >> 6;
  const int wm = wave >> 2, wn = wave & 3;   // 2x4 wave grid; wave output 128x64
  const int ks = lane >> 4;                  // 0..3

#pragma unroll
  for (int i = 0; i < 8; i++)
#pragma unroll
    for (int j = 0; j < 4; j++) acc[i][j] = fx4{0.f, 0.f, 0.f, 0.f};

  // fragment LDS short-offsets (within dbuf), rotation-swizzled
  int aof[8][2], bof[4][2];
#pragma unroll
  for (int mi = 0; mi < 8; mi++) {
    int rh = mi * 16 + (lane & 15);          // row within half-tile
#pragma unroll
    for (int kst = 0; kst < 2; kst++) {
      int p = (kst * 4 + ks + rh) & 7;
      aof[mi][kst] = wm * AH1 + rh * 64 + p * 8;
    }
  }
#pragma unroll
  for (int ni = 0; ni < 4; ni++) {
    int rn = wn * 64 + ni * 16 + (lane & 15);  // B row (=output col) 0..255
    int rh = rn & 127;
#pragma unroll
    for (int kst = 0; kst < 2; kst++) {
      int p = (kst * 4 + ks + rh) & 7;
      bof[ni][kst] = BH0 + (rn >> 7) * AH1 + rh * 64 + p * 8;
    }
  }

  short* buf0 = lds;
  short* buf1 = lds + DBUF_SHORTS;
  // prologue: kt0 fully + kt1 {B-h0, A-h0}
  stage_half(A,  m0,       0, buf0,        tid);
  stage_half(A,  m0 + 128, 0, buf0 + AH1,  tid);
  stage_half(Bt, n0,       0, buf0 + BH0,  tid);
  stage_half(Bt, n0 + 128, 0, buf0 + BH1,  tid);
  stage_half(Bt, n0,       1, buf1 + BH0,  tid);
  stage_half(A,  m0,       1, buf1,        tid);
  WAITVM(4);   // kt0's 8 landed; kt1's 4 in flight
  SBAR();

  for (int kt = 0; kt < NT; ++kt) {
    const short* cb = lds + (kt & 1) * DBUF_SHORTS;
    short* ob  = lds + ((kt & 1) ^ 1) * DBUF_SHORTS;
    short* cbw = lds + (kt & 1) * DBUF_SHORTS;

    // ---- phase 1: read A03 + B01; stage (kt+1, B-h1); MFMA Q0 ----
    sx8 a03[4][2], b01[2][2];
#pragma unroll
    for (int mi = 0; mi < 4; mi++)
#pragma unroll
      for (int kst = 0; kst < 2; kst++) a03[mi][kst] = *(const sx8*)(cb + aof[mi][kst]);
#pragma unroll
    for (int ni = 0; ni < 2; ni++)
#pragma unroll
      for (int kst = 0; kst < 2; kst++) b01[ni][kst] = *(const sx8*)(cb + bof[ni][kst]);
    if (kt + 1 < NT) stage_half(Bt, n0 + 128, kt + 1, ob + BH1, tid);
    WAITLGKM();
    __builtin_amdgcn_sched_barrier(0);
    SBAR();
    __builtin_amdgcn_s_setprio(1);
#pragma unroll
    for (int mi = 0; mi < 4; mi++)
#pragma unroll
      for (int ni = 0; ni < 2; ni++)
#pragma unroll
        for (int kst = 0; kst < 2; kst++)
          acc[mi][ni] = __builtin_amdgcn_mfma_f32_16x16x32_bf16(a03[mi][kst], b01[ni][kst], acc[mi][ni], 0, 0, 0);
    __builtin_amdgcn_s_setprio(0);

    // ---- phase 2: read B23; stage (kt+1, A-h1); MFMA Q1 ----
    sx8 b23[2][2];
#pragma unroll
    for (int ni = 0; ni < 2; ni++)
#pragma unroll
      for (int kst = 0; kst < 2; kst++) b23[ni][kst] = *(const sx8*)(cb + bof[2 + ni][kst]);
    if (kt + 1 < NT) stage_half(A, m0 + 128, kt + 1, ob + AH1, tid);
    WAITLGKM();
    __builtin_amdgcn_sched_barrier(0);
    SBAR();
    __builtin_amdgcn_s_setprio(1);
#pragma unroll
    for (int mi = 0; mi < 4; mi++)
#pragma unroll
      for (int ni = 0; ni < 2; ni++)
#pragma unroll
        for (int kst = 0; kst < 2; kst++)
          acc[mi][2 + ni] = __builtin_amdgcn_mfma_f32_16x16x32_bf16(a03[mi][kst], b23[ni][kst], acc[mi][2 + ni], 0, 0, 0);
    __builtin_amdgcn_s_setprio(0);

    // ---- phase 3: read A47; stage (kt+2, B-h0); MFMA Q2 ----
    sx8 a47[4][2];
#pragma unroll
    for (int mi = 0; mi < 4; mi++)
#pragma unroll
      for (int kst = 0; kst < 2; kst++) a47[mi][kst] = *(const sx8*)(cb + aof[4 + mi][kst]);
    if (kt + 2 < NT) stage_half(Bt, n0, kt + 2, cbw + BH0, tid);
    WAITLGKM();
    __builtin_amdgcn_sched_barrier(0);
    SBAR();
    __builtin_amdgcn_s_setprio(1);
#pragma unroll
    for (int mi = 0; mi < 4; mi++)
#pragma unroll
      for (int ni = 0; ni < 2; ni++)
#pragma unroll
        for (int kst = 0; kst < 2; kst++)
          acc[4 + mi][ni] = __builtin_amdgcn_mfma_f32_16x16x32_bf16(a47[mi][kst], b01[ni][kst], acc[4 + mi][ni], 0, 0, 0);
    __builtin_amdgcn_s_setprio(0);

    // ---- phase 4: stage (kt+2, A-h0); MFMA Q3; tile-boundary vmcnt ----
    if (kt + 2 < NT) stage_half(A, m0, kt + 2, cbw, tid);
    SBAR();
    __builtin_amdgcn_s_setprio(1);
#pragma unroll
    for (int mi = 0; mi < 4; mi++)
#pragma unroll
      for (int ni = 0; ni < 2; ni++)
#pragma unroll
        for (int kst = 0; kst < 2; kst++)
          acc[4 + mi][2 + ni] = __builtin_amdgcn_mfma_f32_16x16x32_bf16(a47[mi][kst], b23[ni][kst], acc[4 + mi][2 + ni], 0, 0, 0);
    __builtin_amdgcn_s_setprio(0);
    if (kt < NT - 2) { WAITVM(4); } else { WAITVM(0); }
    SBAR();
  }
}

// ---------------- GEMM1: xz = x @ W_in[:,1024:] + b_in[1024:], fused epilogue ---------------
__global__ __launch_bounds__(512, 2) void gemm1_kernel(
    const short* __restrict__ xb, const short* __restrict__ Wt1,
    const float* __restrict__ b_in, const float* __restrict__ A_log,
    short* __restrict__ g, float* __restrict__ Bb, float* __restrict__ Cb,
    float* __restrict__ ab) {
  extern __shared__ short lds[];
  const int bid = blockIdx.x;                  // 0..1279
  const int wgid = (bid & 7) * 160 + (bid >> 3);
  const int nt = wgid % 5;
  const int mt = wgid / 5;
  const int m0 = mt * BM;
  const int n0 = nt * BN;
  fx4 acc[8][4];
  gemm_mainloop256(xb, Wt1, m0, n0, lds, acc);

  const int lane = threadIdx.x & 63;
  const int wave = threadIdx.x >> 6;
  const int wm = wave >> 2, wn = wave & 3;

#pragma unroll
  for (int ni = 0; ni < 4; ni++) {
    int n = n0 + wn * 64 + ni * 16 + (lane & 15);
    if (n >= N1) continue;
    float bias = b_in[1024 + n];
#pragma unroll
    for (int mi = 0; mi < 8; mi++) {
#pragma unroll
      for (int r = 0; r < 4; r++) {
        int m = m0 + wm * 128 + mi * 16 + (lane >> 4) * 4 + r;
        float v = acc[mi][ni][r] + bias;
        if (n < 1024) {
          float gl = 0.5f * v * (1.f + erff(v * 0.70710678118654752f));
          g[(long)m * 1024 + n] = f2bf(gl);
        } else if (n < 1040) {
          Bb[m * NSTATE + (n - 1024)] = v;
        } else if (n < 1056) {
          Cb[m * NSTATE + (n - 1040)] = v;
        } else {
          int c = n - 1056;
          float dlt = (v > 20.f) ? v : log1pf(expf(v));
          float Ac = -expf(A_log[c]);
          ab[m * NSTATE + c] = expf(Ac * dlt);
        }
      }
    }
  }
}

// ---- selective scan: serial chain is fma-only; products written per-channel ----
__global__ void scan_kernel(const float* __restrict__ ab, const float* __restrict__ Bb,
                            const float* __restrict__ Cb, float* __restrict__ p) {
  int b = blockIdx.x;
  int ln = threadIdx.x;
  if (ln >= NSTATE) return;
  const float* pa = ab + b * SEQ_LEN * NSTATE + ln;
  const float* pb = Bb + b * SEQ_LEN * NSTATE + ln;
  const float* pc = Cb + b * SEQ_LEN * NSTATE + ln;
  float* po = p + (long)b * SEQ_LEN * NSTATE + ln;
  float s = 0.f;
  float a0[8], b0[8], c0[8], a1[8], b1[8], c1[8];
#pragma unroll
  for (int u = 0; u < 8; u++) {
    int o = u * NSTATE;
    a0[u] = pa[o]; b0[u] = pb[o]; c0[u] = pc[o];
  }
  for (int t0 = 0; t0 < SEQ_LEN; t0 += 16) {
#pragma unroll
    for (int u = 0; u < 8; u++) {
      int o = (t0 + 8 + u) * NSTATE;
      a1[u] = pa[o]; b1[u] = pb[o]; c1[u] = pc[o];
    }
#pragma unroll
    for (int u = 0; u < 8; u++) {
      s = fmaf(a0[u], s, b0[u]);
      po[(t0 + u) * NSTATE] = s * c0[u];
    }
    if (t0 + 16 < SEQ_LEN) {
#pragma unroll
      for (int u = 0; u < 8; u++) {
        int o = (t0 + 16 + u) * NSTATE;
        a0[u] = pa[o]; b0[u] = pb[o]; c0[u] = pc[o];
      }
    }
#pragma unroll
    for (int u = 0; u < 8; u++) {
      s = fmaf(a1[u], s, b1[u]);
      po[(t0 + 8 + u) * NSTATE] = s * c1[u];
    }
  }
}

// ---------------- reduce p over 16 channels -> y ----------------
__global__ void reduce_y_kernel(const float* __restrict__ p, float* __restrict__ y) {
  int m = blockIdx.x * blockDim.x + threadIdx.x;
  const fx4* row = (const fx4*)(p + (long)m * NSTATE);
  fx4 v = row[0] + row[1] + row[2] + row[3];
  y[m] = v[0] + v[1] + v[2] + v[3];
}

// ---------------- GEMM2: out = (y ⊙row g) @ W_out + b_out ----------------
__global__ __launch_bounds__(512, 2) void gemm2_kernel(
    const short* __restrict__ g, const short* __restrict__ Wt2,
    const float* __restrict__ y, const float* __restrict__ b_out,
    float* __restrict__ out) {
  extern __shared__ short lds[];
  const int bid = blockIdx.x;                  // 0..1023
  const int wgid = (bid & 7) * 128 + (bid >> 3);
  const int nt = wgid & 3;
  const int mt = wgid >> 2;
  const int m0 = mt * BM;
  const int n0 = nt * BN;
  fx4 acc[8][4];
  gemm_mainloop256(g, Wt2, m0, n0, lds, acc);

  const int lane = threadIdx.x & 63;
  const int wave = threadIdx.x >> 6;
  const int wm = wave >> 2, wn = wave & 3;

#pragma unroll
  for (int mi = 0; mi < 8; mi++) {
#pragma unroll
    for (int r = 0; r < 4; r++) {
      int m = m0 + wm * 128 + mi * 16 + (lane >> 4) * 4 + r;
      float ym = y[m];
#pragma unroll
      for (int ni = 0; ni < 4; ni++) {
        int n = n0 + wn * 64 + ni * 16 + (lane & 15);
        out[(long)m * 1024 + n] = fmaf(ym, acc[mi][ni][r], b_out[n]);
      }
    }
  }
}

extern "C" void kernel_launch(void* const* d_in, const int* in_sizes, int n_in,
                              void* d_out, int out_size, void* d_ws, size_t ws_size,
                              hipStream_t stream) {
  const float* x     = (const float*)d_in[0];
  const float* W_in  = (const float*)d_in[1];
  const float* b_in  = (const float*)d_in[2];
  const float* A_log = (const float*)d_in[3];
  const float* W_out = (const float*)d_in[4];
  const float* b_out = (const float*)d_in[5];
  float* out = (float*)d_out;

  char* ws = (char*)d_ws;
  short* xb = (short*)ws;  ws += (size_t)MROWS * KDIM * 2;       // 134.2 MB
  short* g  = (short*)ws;  ws += (size_t)MROWS * KDIM * 2;       // 134.2 MB
  short* Wt1 = (short*)ws; ws += (size_t)N1PAD * KDIM * 2;       // 2.6 MB
  short* Wt2 = (short*)ws; ws += (size_t)KDIM * KDIM * 2;        // 2.1 MB
  float* Bb = (float*)ws;  ws += (size_t)MROWS * NSTATE * 4;     // 4.19 MB
  float* Cb = (float*)ws;  ws += (size_t)MROWS * NSTATE * 4;
  float* ab = (float*)ws;  ws += (size_t)MROWS * NSTATE * 4;
  float* p  = (float*)ws;  ws += (size_t)MROWS * NSTATE * 4;
  float* y  = (float*)ws;  ws += (size_t)MROWS * 4;

  convert_x_kernel<<<4096, 256, 0, stream>>>(x, xb, MROWS * KDIM / 8);
  transpose_w_kernel<<<dim3(N1PAD / 32, 32), 256, 0, stream>>>(W_in, Wt1, 2096, 1024, N1);
  transpose_w_kernel<<<dim3(32, 32), 256, 0, stream>>>(W_out, Wt2, 1024, 0, 1024);
  gemm1_kernel<<<MROWS / BM * (N1PAD / BN), 512, 2 * DBUF_SHORTS * 2, stream>>>(
      xb, Wt1, b_in, A_log, g, Bb, Cb, ab);
  scan_kernel<<<NBATCH, 64, 0, stream>>>(ab, Bb, Cb, p);
  reduce_y_kernel<<<MROWS / 256, 256, 0, stream>>>(p, y);
  gemm2_kernel<<<MROWS / BM * (KDIM / BN), 512, 2 * DBUF_SHORTS * 2, stream>>>(
      g, Wt2, y, b_out, out);
}

// Round 7
// 657.393 us; speedup vs baseline: 1.1514x; 1.0384x over previous
//
#include <hip/hip_runtime.h>
#include <cstdint>

typedef float fx4 __attribute__((ext_vector_type(4)));
typedef short sx8 __attribute__((ext_vector_type(8)));

#define NSTATE 16
#define SEQ_LEN 2048
#define NBATCH 32
#define MROWS 65536           // NBATCH*SEQ_LEN
#define KDIM 1024
#define N1 1072               // z(1024) + B(16) + C(16) + delta(16)
#define N1PAD 1152            // 9 tiles of 128
#define BM 128
#define BN 128
#define BK 32
#define NSTEP (KDIM / BK)     // 32
#define RING 3
#define SLOT_SHORTS 4096      // 128x32 bf16 = 8KB per matrix per slot

__device__ __forceinline__ short f2bf(float f) {
  unsigned u = __float_as_uint(f);
  u += 0x7FFFu + ((u >> 16) & 1u);   // round-to-nearest-even
  return (short)(u >> 16);
}

// A&S 7.1.26 erf, |eps|<=1.5e-7, branchless. gelu(x)=0.5x(1+erf(x/sqrt2))
__device__ __forceinline__ float gelu_exact(float x) {
  float ax = fabsf(x) * 0.70710678118654752f;
  float t = __builtin_amdgcn_rcpf(fmaf(0.3275911f, ax, 1.0f));
  float p = fmaf(1.061405429f, t, -1.453152027f);
  p = fmaf(p, t, 1.421413741f);
  p = fmaf(p, t, -0.284496736f);
  p = fmaf(p, t, 0.254829592f);
  p = p * t;
  float e = __expf(-ax * ax);
  float erfv = fmaf(-p, e, 1.0f);
  erfv = copysignf(erfv, x);
  return 0.5f * x * (1.0f + erfv);
}

#define GLOAD_LDS16(gp, lp)                                                          \
  __builtin_amdgcn_global_load_lds(                                                  \
      (const __attribute__((address_space(1))) unsigned int*)(gp),                   \
      (__attribute__((address_space(3))) unsigned int*)(lp), 16, 0, 0)

#define SBAR() __builtin_amdgcn_s_barrier()

// ---------------- convert x (fp32 -> bf16) ----------------
__global__ void convert_x_kernel(const float* __restrict__ x, short* __restrict__ xb, int n8) {
  int i = blockIdx.x * blockDim.x + threadIdx.x;
  int stride = gridDim.x * blockDim.x;
  for (; i < n8; i += stride) {
    const fx4* p = (const fx4*)(x + (long)i * 8);
    fx4 a = p[0], b = p[1];
    sx8 o;
    o[0] = f2bf(a[0]); o[1] = f2bf(a[1]); o[2] = f2bf(a[2]); o[3] = f2bf(a[3]);
    o[4] = f2bf(b[0]); o[5] = f2bf(b[1]); o[6] = f2bf(b[2]); o[7] = f2bf(b[3]);
    *(sx8*)(xb + (long)i * 8) = o;
  }
}

// ------------- transpose weights to (N x K) bf16, zero-pad rows -------------
__global__ void transpose_w_kernel(const float* __restrict__ src, short* __restrict__ dst,
                                   int src_cols, int col_off, int valid_rows) {
  __shared__ float t[32][33];
  int j0 = blockIdx.x * 32;
  int k0 = blockIdx.y * 32;
  int c = threadIdx.x & 31;
  int r = threadIdx.x >> 5;  // 0..7
#pragma unroll
  for (int i = 0; i < 4; i++) {
    int k = k0 + r + i * 8;
    int j = j0 + c;
    float v = (j < valid_rows) ? src[(long)k * src_cols + col_off + j] : 0.f;
    t[r + i * 8][c] = v;
  }
  __syncthreads();
#pragma unroll
  for (int i = 0; i < 4; i++) {
    int j = j0 + r + i * 8;
    dst[(long)j * 1024 + k0 + c] = f2bf(t[c][r + i * 8]);
  }
}

// ---- 128x128 mainloop: ring-3 LDS, ~2.5-step prefetch, rotation swizzle ----
// LDS physical slot p at row r holds logical k-slot q=(p-(r>>1))&3 (read: p=(ks+(r>>1))&3).
// Chunk j (16B unit): r=j>>2, p=j&3 -> global kslot q=((j&3)-((j>>3)&3))&3. Dest linear in j.
__device__ __forceinline__ void gemm_mainloop(const short* __restrict__ A,
                                              const short* __restrict__ Bt,
                                              int m0, int n0,
                                              short* AshR, short* BshR,
                                              fx4 acc[4][4]) {
  const int tid = threadIdx.x;
  const int lane = tid & 63;
  const int wave = tid >> 6;
  const int wm = wave >> 1, wn = wave & 1;
  const int ks = lane >> 4;

#pragma unroll
  for (int i = 0; i < 4; i++)
#pragma unroll
    for (int j = 0; j < 4; j++) acc[i][j] = fx4{0.f, 0.f, 0.f, 0.f};

  const int j0 = wave * 64 + lane;           // 0..255
  const int j1 = 256 + j0;                   // 256..511
  const int q0 = ((j0 & 3) - ((j0 >> 3) & 3)) & 3;
  const int q1 = ((j1 & 3) - ((j1 >> 3) & 3)) & 3;
  const short* a0 = A + (long)(m0 + (j0 >> 2)) * KDIM + q0 * 8;
  const short* a1 = A + (long)(m0 + (j1 >> 2)) * KDIM + q1 * 8;
  const short* b0 = Bt + (long)(n0 + (j0 >> 2)) * KDIM + q0 * 8;
  const short* b1 = Bt + (long)(n0 + (j1 >> 2)) * KDIM + q1 * 8;
  const int d0 = j0 * 8, d1 = j1 * 8;        // linear LDS short offsets

  // fragment read offsets (swizzled)
  int aof[4], bof[4];
#pragma unroll
  for (int i = 0; i < 4; i++) {
    int rr = wm * 64 + i * 16 + (lane & 15);
    aof[i] = rr * 32 + ((ks + ((rr >> 1) & 3)) & 3) * 8;
  }
#pragma unroll
  for (int j = 0; j < 4; j++) {
    int rn = wn * 64 + j * 16 + (lane & 15);
    bof[j] = rn * 32 + ((ks + ((rn >> 1) & 3)) & 3) * 8;
  }

  // prologue: stage steps 0,1,2 into slots 0,1,2
#pragma unroll
  for (int s = 0; s < RING; s++) {
    short* sa = AshR + s * SLOT_SHORTS;
    short* sb = BshR + s * SLOT_SHORTS;
    GLOAD_LDS16(a0 + s * BK, sa + d0);
    GLOAD_LDS16(a1 + s * BK, sa + d1);
    GLOAD_LDS16(b0 + s * BK, sb + d0);
    GLOAD_LDS16(b1 + s * BK, sb + d1);
  }

  int slot = 0;
  for (int s = 0; s < NSTEP; ++s) {
    // wait: newest 2 stage-groups (8 loads) may remain in flight; step-s data complete
    if (s <= NSTEP - 3)      asm volatile("s_waitcnt vmcnt(8)" ::: "memory");
    else if (s == NSTEP - 2) asm volatile("s_waitcnt vmcnt(4)" ::: "memory");
    else                     asm volatile("s_waitcnt vmcnt(0)" ::: "memory");
    SBAR();                                    // slot data visible to all waves

    const short* sa = AshR + slot * SLOT_SHORTS;
    const short* sb = BshR + slot * SLOT_SHORTS;
    sx8 af[4], bfr[4];
#pragma unroll
    for (int i = 0; i < 4; i++) af[i] = *(const sx8*)(sa + aof[i]);
#pragma unroll
    for (int j = 0; j < 4; j++) bfr[j] = *(const sx8*)(sb + bof[j]);
    asm volatile("s_waitcnt lgkmcnt(0)" ::: "memory");
    __builtin_amdgcn_sched_barrier(0);

    __builtin_amdgcn_s_setprio(1);
#pragma unroll
    for (int i = 0; i < 4; i++)
#pragma unroll
      for (int j = 0; j < 4; j++)
        acc[i][j] = __builtin_amdgcn_mfma_f32_16x16x32_bf16(af[i], bfr[j], acc[i][j], 0, 0, 0);
    __builtin_amdgcn_s_setprio(0);

    SBAR();                                    // all waves done reading this slot
    if (s + RING < NSTEP) {                    // overwrite this slot with step s+3
      short* wa = AshR + slot * SLOT_SHORTS;
      short* wb = BshR + slot * SLOT_SHORTS;
      GLOAD_LDS16(a0 + (s + RING) * BK, wa + d0);
      GLOAD_LDS16(a1 + (s + RING) * BK, wa + d1);
      GLOAD_LDS16(b0 + (s + RING) * BK, wb + d0);
      GLOAD_LDS16(b1 + (s + RING) * BK, wb + d1);
    }
    slot = (slot == RING - 1) ? 0 : slot + 1;
  }
}

// ---------------- GEMM1: xz = x @ W_in[:,1024:] + b_in[1024:], fused epilogue ---------------
__global__ __launch_bounds__(256, 3) void gemm1_kernel(
    const short* __restrict__ xb, const short* __restrict__ Wt1,
    const float* __restrict__ b_in, const float* __restrict__ A_log,
    short* __restrict__ g, float* __restrict__ Bb, float* __restrict__ Cb,
    float* __restrict__ ab) {
  __shared__ short Ash[RING * SLOT_SHORTS] __attribute__((aligned(16)));
  __shared__ short Bsh[RING * SLOT_SHORTS] __attribute__((aligned(16)));
  const int bid = blockIdx.x;                 // 0..4607
  const int wgid = (bid & 7) * 576 + (bid >> 3);
  const int nt = wgid % 9;
  const int mt = wgid / 9;
  const int m0 = mt * BM;
  const int n0 = nt * BN;
  fx4 acc[4][4];
  gemm_mainloop(xb, Wt1, m0, n0, Ash, Bsh, acc);

  const int lane = threadIdx.x & 63;
  const int wave = threadIdx.x >> 6;
  const int wm = wave >> 1, wn = wave & 1;

#pragma unroll
  for (int j = 0; j < 4; j++) {
    int n = n0 + wn * 64 + j * 16 + (lane & 15);
    if (n >= N1) continue;
    float bias = b_in[1024 + n];
#pragma unroll
    for (int i = 0; i < 4; i++) {
#pragma unroll
      for (int r = 0; r < 4; r++) {
        int m = m0 + wm * 64 + i * 16 + (lane >> 4) * 4 + r;
        float v = acc[i][j][r] + bias;
        if (n < 1024) {
          g[(long)m * 1024 + n] = f2bf(gelu_exact(v));
        } else if (n < 1040) {
          Bb[m * NSTATE + (n - 1024)] = v;
        } else if (n < 1056) {
          Cb[m * NSTATE + (n - 1040)] = v;
        } else {
          int c = n - 1056;
          float dlt = (v > 20.f) ? v : log1pf(expf(v));
          float Ac = -expf(A_log[c]);
          ab[m * NSTATE + c] = expf(Ac * dlt);
        }
      }
    }
  }
}

// ---- selective scan: serial chain is fma-only; products written per-channel ----
__global__ void scan_kernel(const float* __restrict__ ab, const float* __restrict__ Bb,
                            const float* __restrict__ Cb, float* __restrict__ p) {
  int b = blockIdx.x;
  int ln = threadIdx.x;
  if (ln >= NSTATE) return;
  const float* pa = ab + b * SEQ_LEN * NSTATE + ln;
  const float* pb = Bb + b * SEQ_LEN * NSTATE + ln;
  const float* pc = Cb + b * SEQ_LEN * NSTATE + ln;
  float* po = p + (long)b * SEQ_LEN * NSTATE + ln;
  float s = 0.f;
  float a0[8], b0[8], c0[8], a1[8], b1[8], c1[8];
#pragma unroll
  for (int u = 0; u < 8; u++) {
    int o = u * NSTATE;
    a0[u] = pa[o]; b0[u] = pb[o]; c0[u] = pc[o];
  }
  for (int t0 = 0; t0 < SEQ_LEN; t0 += 16) {
#pragma unroll
    for (int u = 0; u < 8; u++) {
      int o = (t0 + 8 + u) * NSTATE;
      a1[u] = pa[o]; b1[u] = pb[o]; c1[u] = pc[o];
    }
#pragma unroll
    for (int u = 0; u < 8; u++) {
      s = fmaf(a0[u], s, b0[u]);
      po[(t0 + u) * NSTATE] = s * c0[u];
    }
    if (t0 + 16 < SEQ_LEN) {
#pragma unroll
      for (int u = 0; u < 8; u++) {
        int o = (t0 + 16 + u) * NSTATE;
        a0[u] = pa[o]; b0[u] = pb[o]; c0[u] = pc[o];
      }
    }
#pragma unroll
    for (int u = 0; u < 8; u++) {
      s = fmaf(a1[u], s, b1[u]);
      po[(t0 + 8 + u) * NSTATE] = s * c1[u];
    }
  }
}

// ---------------- reduce p over 16 channels -> y ----------------
__global__ void reduce_y_kernel(const float* __restrict__ p, float* __restrict__ y) {
  int m = blockIdx.x * blockDim.x + threadIdx.x;
  const fx4* row = (const fx4*)(p + (long)m * NSTATE);
  fx4 v = row[0] + row[1] + row[2] + row[3];
  y[m] = v[0] + v[1] + v[2] + v[3];
}

// ---------------- GEMM2: out = (y ⊙row g) @ W_out + b_out ----------------
__global__ __launch_bounds__(256, 3) void gemm2_kernel(
    const short* __restrict__ g, const short* __restrict__ Wt2,
    const float* __restrict__ y, const float* __restrict__ b_out,
    float* __restrict__ out) {
  __shared__ short Ash[RING * SLOT_SHORTS] __attribute__((aligned(16)));
  __shared__ short Bsh[RING * SLOT_SHORTS] __attribute__((aligned(16)));
  const int bid = blockIdx.x;                 // 0..4095
  const int wgid = (bid & 7) * 512 + (bid >> 3);
  const int nt = wgid & 7;
  const int mt = wgid >> 3;
  const int m0 = mt * BM;
  const int n0 = nt * BN;
  fx4 acc[4][4];
  gemm_mainloop(g, Wt2, m0, n0, Ash, Bsh, acc);

  const int lane = threadIdx.x & 63;
  const int wave = threadIdx.x >> 6;
  const int wm = wave >> 1, wn = wave & 1;

#pragma unroll
  for (int i = 0; i < 4; i++) {
#pragma unroll
    for (int r = 0; r < 4; r++) {
      int m = m0 + wm * 64 + i * 16 + (lane >> 4) * 4 + r;
      float ym = y[m];
#pragma unroll
      for (int j = 0; j < 4; j++) {
        int n = n0 + wn * 64 + j * 16 + (lane & 15);
        out[(long)m * 1024 + n] = fmaf(ym, acc[i][j][r], b_out[n]);
      }
    }
  }
}

extern "C" void kernel_launch(void* const* d_in, const int* in_sizes, int n_in,
                              void* d_out, int out_size, void* d_ws, size_t ws_size,
                              hipStream_t stream) {
  const float* x     = (const float*)d_in[0];
  const float* W_in  = (const float*)d_in[1];
  const float* b_in  = (const float*)d_in[2];
  const float* A_log = (const float*)d_in[3];
  const float* W_out = (const float*)d_in[4];
  const float* b_out = (const float*)d_in[5];
  float* out = (float*)d_out;

  char* ws = (char*)d_ws;
  short* xb = (short*)ws;  ws += (size_t)MROWS * KDIM * 2;       // 134.2 MB
  short* g  = (short*)ws;  ws += (size_t)MROWS * KDIM * 2;       // 134.2 MB
  short* Wt1 = (short*)ws; ws += (size_t)N1PAD * KDIM * 2;       // 2.36 MB
  short* Wt2 = (short*)ws; ws += (size_t)KDIM * KDIM * 2;        // 2.10 MB
  float* Bb = (float*)ws;  ws += (size_t)MROWS * NSTATE * 4;     // 4.19 MB
  float* Cb = (float*)ws;  ws += (size_t)MROWS * NSTATE * 4;
  float* ab = (float*)ws;  ws += (size_t)MROWS * NSTATE * 4;
  float* p  = (float*)ws;  ws += (size_t)MROWS * NSTATE * 4;
  float* y  = (float*)ws;  ws += (size_t)MROWS * 4;

  convert_x_kernel<<<4096, 256, 0, stream>>>(x, xb, MROWS * KDIM / 8);
  transpose_w_kernel<<<dim3(N1PAD / 32, 32), 256, 0, stream>>>(W_in, Wt1, 2096, 1024, N1);
  transpose_w_kernel<<<dim3(32, 32), 256, 0, stream>>>(W_out, Wt2, 1024, 0, 1024);
  gemm1_kernel<<<MROWS / BM * (N1PAD / BN), 256, 0, stream>>>(xb, Wt1, b_in, A_log, g, Bb, Cb, ab);
  scan_kernel<<<NBATCH, 64, 0, stream>>>(ab, Bb, Cb, p);
  reduce_y_kernel<<<MROWS / 256, 256, 0, stream>>>(p, y);
  gemm2_kernel<<<MROWS / BM * (KDIM / BN), 256, 0, stream>>>(g, Wt2, y, b_out, out);
}